// Round 8
// baseline (495.162 us; speedup 1.0000x reference)
//
#include <hip/hip_runtime.h>
#include <hip/hip_bf16.h>

#define NN 100000
#define NE 600000
#define HH 128
#define NB 4
#define TILE 2048
#define NTILES ((NN + TILE - 1) / TILE)   // 49

typedef __attribute__((ext_vector_type(8))) short bf16x8;
typedef __attribute__((ext_vector_type(4))) float f32x4;
typedef __attribute__((ext_vector_type(4))) float vfloat4;
typedef __attribute__((ext_vector_type(4))) unsigned short ushort4v;

// round-to-nearest-even f32 -> bf16 bits (inputs are finite)
static __device__ __forceinline__ short f2bf(float f) {
  unsigned u = __float_as_uint(f);
  unsigned r = (u + 0x7fffu + ((u >> 16) & 1u)) >> 16;
  return (short)r;
}

static __device__ __forceinline__ float bf2f(short s) {
  unsigned u = (unsigned)(unsigned short)s;
  return __uint_as_float(u << 16);
}

// W8[kb][o][j] = W[o][k=kb*8+j], kb in [0,80), o in [0,128), j in [0,8).
// W[o][k]: k<512 -> V[k>>7][k&127][o] (= V flat [k*128+o]); else loopW[k-512][o].
__global__ __launch_bounds__(256) void build_wt(const float* __restrict__ V,
                                                const float* __restrict__ loopW,
                                                short* __restrict__ W8)
{
  int idx = blockIdx.x * blockDim.x + threadIdx.x;   // 320*256 = 81920
  int j  = idx & 7;
  int o  = (idx >> 3) & 127;
  int kb = idx >> 10;
  int k  = kb * 8 + j;
  float v;
  if (k < 512) v = V[(size_t)k * HH + o];
  else         v = loopW[(size_t)(k - 512) * HH + o];
  W8[idx] = f2bf(v);
}

// hbf = bf16(emb), vectorized (8 elems/thread/iter)
__global__ __launch_bounds__(256) void cast_h(const float* __restrict__ in,
                                              short* __restrict__ out)
{
  const int n8 = NN * HH / 8;
  for (int i = blockIdx.x * blockDim.x + threadIdx.x; i < n8; i += gridDim.x * blockDim.x) {
    const vfloat4* p = reinterpret_cast<const vfloat4*>(in + i * 8);
    vfloat4 a = p[0], b = p[1];
    bf16x8 o;
#pragma unroll
    for (int j = 0; j < 4; ++j) { o[j] = f2bf(a[j]); o[j + 4] = f2bf(b[j]); }
    reinterpret_cast<bf16x8*>(out)[i] = o;
  }
}

// ---------------- CSR build ----------------

__global__ __launch_bounds__(256) void hist_deg(const int* __restrict__ dst,
                                                int* __restrict__ deg)
{
  int e = blockIdx.x * blockDim.x + threadIdx.x;
  if (e < NE) atomicAdd(&deg[dst[e]], 1);
}

__global__ __launch_bounds__(256) void scan_tiles(const int* __restrict__ deg,
                                                  int* __restrict__ tilesum)
{
  __shared__ int red[256];
  const int tid = threadIdx.x;
  int base = blockIdx.x * TILE + tid * 8;
  int s = 0;
#pragma unroll
  for (int j = 0; j < 8; ++j) {
    int i = base + j;
    if (i < NN) s += deg[i];
  }
  red[tid] = s;
  __syncthreads();
  for (int off = 128; off > 0; off >>= 1) {
    if (tid < off) red[tid] += red[tid + off];
    __syncthreads();
  }
  if (tid == 0) tilesum[blockIdx.x] = red[0];
}

__global__ __launch_bounds__(256) void scan_final(const int* deg,
                                                  const int* __restrict__ tilesum,
                                                  int* __restrict__ rowptr,
                                                  int* cursor)
{
  __shared__ int lds[256];
  const int tid = threadIdx.x;
  int pre = 0;
  for (int t = 0; t < NTILES; ++t)
    if (t < blockIdx.x) pre += tilesum[t];

  int base = blockIdx.x * TILE + tid * 8;
  int d[8];
  int s = 0;
#pragma unroll
  for (int j = 0; j < 8; ++j) {
    int i = base + j;
    d[j] = (i < NN) ? deg[i] : 0;
    s += d[j];
  }
  lds[tid] = s;
  __syncthreads();
  for (int off = 1; off < 256; off <<= 1) {
    int t = (tid >= off) ? lds[tid - off] : 0;
    __syncthreads();
    lds[tid] += t;
    __syncthreads();
  }
  int run = pre + lds[tid] - s;
#pragma unroll
  for (int j = 0; j < 8; ++j) {
    int i = base + j;
    if (i < NN) {
      rowptr[i] = run;
      cursor[i] = run;
      run += d[j];
    }
  }
  if (blockIdx.x == NTILES - 1 && tid == 255)
    rowptr[NN] = pre + lds[255];
}

__global__ __launch_bounds__(256) void scatter_edges(
    const int* __restrict__ src, const int* __restrict__ dst, const int* __restrict__ ety,
    int* __restrict__ cursor, int* __restrict__ csr)
{
  int e = blockIdx.x * blockDim.x + threadIdx.x;
  if (e >= NE) return;
  int d = dst[e];
  int p = atomicAdd(&cursor[d], 1);
  csr[p] = src[e] | (ety[e] << 20);            // src:20 bits, ety:3 bits
}

// ---------------- Fused layer: gather (LDS) + GEMM ----------------
// Block = 64 dst nodes. Phase 1: wave w gathers nodes w*16..w*16+15:
//   gl[row][b*128+i] accum = sum_e comp[et][b]*h[src][i], written bf16 to LDS
//   with XOR slot swizzle (slot ^ (row&7)) to break the GEMM read conflict.
// Phase 2: out[n][o] = sum_k [gl(n) | h(n)][k] * W[o][k], K=640, W LDS-staged
// in 8KB double-buffered slices (R7-validated). h fragments prefetched to regs.
// FINAL=0: bf16 relu(x+bias) -> next layer hbf.  FINAL=1: fp32 x+bias -> d_out.
// NOTE: no early returns -- every thread reaches every __syncthreads.
template<int FINAL>
__global__ __launch_bounds__(256, 2) void rgcn_layer(
    const int* __restrict__ rowptr, const int* __restrict__ csr,
    const float* __restrict__ comp,   // [R,B]
    const short* __restrict__ hbf,    // [N,128] bf16
    const short* __restrict__ W8,     // [80][128][8] bf16 (slot = kb*128+o)
    const float* __restrict__ bias,   // [128]
    short* __restrict__ outH,         // [N,128] bf16 (FINAL=0)
    float* __restrict__ outF)         // [N,128] fp32 (FINAL=1)
{
  __shared__ bf16x8 gl[64][64];       // 64 KB gathered-g tile (swizzled slots)
  __shared__ bf16x8 wl[2][512];       // 16 KB W slice double-buffer

  const int tid  = threadIdx.x;
  const int wave = tid >> 6;
  const int lane = tid & 63;
  const int b  = lane >> 4;           // basis (gather) / k-group g8 (gemm)
  const int q  = lane & 15;           // col-slot (gather) / node r (gemm)
  const int base = blockIdx.x * 64;

  // --- prefetch self-loop h fragments for the gemm phase (lane = (q=r, b=g8)) ---
  const int myrow  = wave * 16 + q;
  const int mynode = base + myrow;
  const bool myvalid = (mynode < NN);
  const bf16x8* ha = reinterpret_cast<const bf16x8*>(hbf + (size_t)(myvalid ? mynode : 0) * HH);
  bf16x8 hreg[4];
#pragma unroll
  for (int j = 0; j < 4; ++j) hreg[j] = ha[j * 4 + b];

  // ---------------- phase 1: gather ----------------
#pragma unroll 1
  for (int nn = 0; nn < 16; ++nn) {
    const int row = wave * 16 + nn;
    const int node = base + row;
    int start = 0, end = 0;
    if (node < NN) { start = rowptr[node]; end = rowptr[node + 1]; }

    float acc[8] = {0.f, 0.f, 0.f, 0.f, 0.f, 0.f, 0.f, 0.f};
    int i = start;
    for (; i + 4 <= end; i += 4) {
      int e0 = csr[i], e1 = csr[i + 1], e2 = csr[i + 2], e3 = csr[i + 3];
      bf16x8 h0 = reinterpret_cast<const bf16x8*>(hbf + (size_t)(e0 & 0xFFFFF) * HH)[q];
      bf16x8 h1 = reinterpret_cast<const bf16x8*>(hbf + (size_t)(e1 & 0xFFFFF) * HH)[q];
      bf16x8 h2 = reinterpret_cast<const bf16x8*>(hbf + (size_t)(e2 & 0xFFFFF) * HH)[q];
      bf16x8 h3 = reinterpret_cast<const bf16x8*>(hbf + (size_t)(e3 & 0xFFFFF) * HH)[q];
      float c0 = comp[(e0 >> 20) * NB + b];
      float c1 = comp[(e1 >> 20) * NB + b];
      float c2 = comp[(e2 >> 20) * NB + b];
      float c3 = comp[(e3 >> 20) * NB + b];
#pragma unroll
      for (int j = 0; j < 8; ++j) acc[j] += bf2f(h0[j]) * c0;
#pragma unroll
      for (int j = 0; j < 8; ++j) acc[j] += bf2f(h1[j]) * c1;
#pragma unroll
      for (int j = 0; j < 8; ++j) acc[j] += bf2f(h2[j]) * c2;
#pragma unroll
      for (int j = 0; j < 8; ++j) acc[j] += bf2f(h3[j]) * c3;
    }
    for (; i < end; ++i) {
      int e0 = csr[i];
      bf16x8 h0 = reinterpret_cast<const bf16x8*>(hbf + (size_t)(e0 & 0xFFFFF) * HH)[q];
      float c0 = comp[(e0 >> 20) * NB + b];
#pragma unroll
      for (int j = 0; j < 8; ++j) acc[j] += bf2f(h0[j]) * c0;
    }

    bf16x8 o;
#pragma unroll
    for (int j = 0; j < 8; ++j) o[j] = f2bf(acc[j]);
    // logical slot = b*16+q = lane; phys = slot ^ (row&7); row&7 == nn&7
    gl[row][lane ^ (nn & 7)] = o;
  }

  // stage W slice 0 (coalesced, 2 slots/thread)
  const bf16x8* wsrc = reinterpret_cast<const bf16x8*>(W8);
  wl[0][tid]       = wsrc[tid];
  wl[0][tid + 256] = wsrc[tid + 256];
  __syncthreads();

  // ---------------- phase 2: GEMM ----------------
  const int r  = q;
  const int g8 = b;

  f32x4 acc[8];
#pragma unroll
  for (int ct = 0; ct < 8; ++ct) acc[ct] = (f32x4){0.f, 0.f, 0.f, 0.f};

#pragma unroll 1
  for (int ks = 0; ks < 20; ++ks) {
    const int cur = ks & 1;
    if (ks < 19) {
      bf16x8 n0 = wsrc[(ks + 1) * 512 + tid];
      bf16x8 n1 = wsrc[(ks + 1) * 512 + 256 + tid];
      wl[cur ^ 1][tid]       = n0;
      wl[cur ^ 1][tid + 256] = n1;
    }
    // A fragment: k = ks*32 + g8*8 + j ; logical slot = ks*4+g8
    bf16x8 a = (ks < 16) ? gl[myrow][(ks * 4 + g8) ^ (r & 7)] : hreg[ks - 16];
#pragma unroll
    for (int ct = 0; ct < 8; ++ct) {
      bf16x8 w = wl[cur][g8 * 128 + ct * 16 + r];
      acc[ct] = __builtin_amdgcn_mfma_f32_16x16x32_bf16(w, a, acc[ct], 0, 0, 0);
    }
    __syncthreads();
  }

  // epilogue: D mapping (verified): node = r, o = ct*16 + g8*4 + reg
#pragma unroll
  for (int ct = 0; ct < 8; ++ct) {
    const int o = ct * 16 + g8 * 4;
    vfloat4 bs = *reinterpret_cast<const vfloat4*>(bias + o);
    if (FINAL) {
      vfloat4 x;
#pragma unroll
      for (int rr = 0; rr < 4; ++rr) x[rr] = acc[ct][rr] + bs[rr];
      if (myvalid) reinterpret_cast<vfloat4*>(outF + (size_t)mynode * HH)[ct * 4 + g8] = x;
    } else {
      ushort4v s;
#pragma unroll
      for (int rr = 0; rr < 4; ++rr)
        s[rr] = (unsigned short)f2bf(fmaxf(acc[ct][rr] + bs[rr], 0.f));
      if (myvalid) reinterpret_cast<ushort4v*>(outH + (size_t)mynode * HH)[ct * 4 + g8] = s;
    }
  }
}

extern "C" void kernel_launch(void* const* d_in, const int* in_sizes, int n_in,
                              void* d_out, int out_size, void* d_ws, size_t ws_size,
                              hipStream_t stream)
{
  const int*   srcp  = (const int*)d_in[1];
  const int*   dstp  = (const int*)d_in[2];
  const int*   etp   = (const int*)d_in[3];
  const float* emb   = (const float*)d_in[4];
  const float* V1    = (const float*)d_in[5];
  const float* comp1 = (const float*)d_in[6];
  const float* loop1 = (const float*)d_in[7];
  const float* bias1 = (const float*)d_in[8];
  const float* V2    = (const float*)d_in[9];
  const float* comp2 = (const float*)d_in[10];
  const float* loop2 = (const float*)d_in[11];
  const float* bias2 = (const float*)d_in[12];
  float* out = (float*)d_out;

  char* ws = (char*)d_ws;
  short* Wt1     = (short*)(ws);                         // 163,840 B
  short* Wt2     = (short*)(ws + 163840);                // 163,840 B
  short* hbf1    = (short*)(ws + 327680);                // 25,600,000 B
  short* hbf2    = (short*)(ws + 25927680);              // 25,600,000 B
  int*   deg     = (int*)  (ws + 51527680);              // 400,000 B (doubles as cursor)
  int*   rowptr  = (int*)  (ws + 51927680);              // 400,004 B
  int*   csr     = (int*)  (ws + 52327696);              // 2,400,000 B
  int*   tilesum = (int*)  (ws + 54727696);              // 196 B  (total ~54.7 MB)

  const int layer_blocks = (NN + 63) / 64;               // 1563
  const int e_blocks     = (NE + 255) / 256;

  // --- CSR build (once, reused by both layers) ---
  hipMemsetAsync(deg, 0, NN * sizeof(int), stream);
  hipLaunchKernelGGL(hist_deg, dim3(e_blocks), dim3(256), 0, stream, dstp, deg);
  hipLaunchKernelGGL(scan_tiles, dim3(NTILES), dim3(256), 0, stream, deg, tilesum);
  hipLaunchKernelGGL(scan_final, dim3(NTILES), dim3(256), 0, stream,
                     deg, tilesum, rowptr, deg);
  hipLaunchKernelGGL(scatter_edges, dim3(e_blocks), dim3(256), 0, stream,
                     srcp, dstp, etp, deg, csr);

  hipLaunchKernelGGL(build_wt, dim3(320), dim3(256), 0, stream, V1, loop1, Wt1);
  hipLaunchKernelGGL(build_wt, dim3(320), dim3(256), 0, stream, V2, loop2, Wt2);
  hipLaunchKernelGGL(cast_h, dim3(2048), dim3(256), 0, stream, emb, hbf1);

  // Layer 1 (fused gather+GEMM, bf16 relu output)
  hipLaunchKernelGGL((rgcn_layer<0>), dim3(layer_blocks), dim3(256), 0, stream,
                     rowptr, csr, comp1, hbf1, Wt1, bias1, hbf2, (float*)nullptr);

  // Layer 2 (fused, fp32 output)
  hipLaunchKernelGGL((rgcn_layer<1>), dim3(layer_blocks), dim3(256), 0, stream,
                     rowptr, csr, comp2, hbf2, Wt2, bias2, (short*)nullptr, out);
}

// Round 9
// 357.368 us; speedup vs baseline: 1.3856x; 1.3856x over previous
//
#include <hip/hip_runtime.h>
#include <hip/hip_bf16.h>

#define NN 100000
#define NE 600000
#define HH 128
#define NB 4
#define TILE 2048
#define NTILES ((NN + TILE - 1) / TILE)   // 49

typedef __attribute__((ext_vector_type(8))) short bf16x8;
typedef __attribute__((ext_vector_type(4))) float f32x4;
typedef __attribute__((ext_vector_type(4))) float vfloat4;
typedef __attribute__((ext_vector_type(4))) unsigned short ushort4v;

// round-to-nearest-even f32 -> bf16 bits (inputs are finite)
static __device__ __forceinline__ short f2bf(float f) {
  unsigned u = __float_as_uint(f);
  unsigned r = (u + 0x7fffu + ((u >> 16) & 1u)) >> 16;
  return (short)r;
}

static __device__ __forceinline__ float bf2f(short s) {
  unsigned u = (unsigned)(unsigned short)s;
  return __uint_as_float(u << 16);
}

// W8[kb][o][j] = W[o][k=kb*8+j], kb in [0,80), o in [0,128), j in [0,8).
// W[o][k]: k<512 -> V[k>>7][k&127][o] (= V flat [k*128+o]); else loopW[k-512][o].
__global__ __launch_bounds__(256) void build_wt(const float* __restrict__ V,
                                                const float* __restrict__ loopW,
                                                short* __restrict__ W8)
{
  int idx = blockIdx.x * blockDim.x + threadIdx.x;   // 320*256 = 81920
  int j  = idx & 7;
  int o  = (idx >> 3) & 127;
  int kb = idx >> 10;
  int k  = kb * 8 + j;
  float v;
  if (k < 512) v = V[(size_t)k * HH + o];
  else         v = loopW[(size_t)(k - 512) * HH + o];
  W8[idx] = f2bf(v);
}

// hbf = bf16(emb), vectorized (8 elems/thread/iter)
__global__ __launch_bounds__(256) void cast_h(const float* __restrict__ in,
                                              short* __restrict__ out)
{
  const int n8 = NN * HH / 8;
  for (int i = blockIdx.x * blockDim.x + threadIdx.x; i < n8; i += gridDim.x * blockDim.x) {
    const vfloat4* p = reinterpret_cast<const vfloat4*>(in + i * 8);
    vfloat4 a = p[0], b = p[1];
    bf16x8 o;
#pragma unroll
    for (int j = 0; j < 4; ++j) { o[j] = f2bf(a[j]); o[j + 4] = f2bf(b[j]); }
    reinterpret_cast<bf16x8*>(out)[i] = o;
  }
}

// ---------------- CSR build ----------------

__global__ __launch_bounds__(256) void hist_deg(const int* __restrict__ dst,
                                                int* __restrict__ deg)
{
  int e = blockIdx.x * blockDim.x + threadIdx.x;
  if (e < NE) atomicAdd(&deg[dst[e]], 1);
}

__global__ __launch_bounds__(256) void scan_tiles(const int* __restrict__ deg,
                                                  int* __restrict__ tilesum)
{
  __shared__ int red[256];
  const int tid = threadIdx.x;
  int base = blockIdx.x * TILE + tid * 8;
  int s = 0;
#pragma unroll
  for (int j = 0; j < 8; ++j) {
    int i = base + j;
    if (i < NN) s += deg[i];
  }
  red[tid] = s;
  __syncthreads();
  for (int off = 128; off > 0; off >>= 1) {
    if (tid < off) red[tid] += red[tid + off];
    __syncthreads();
  }
  if (tid == 0) tilesum[blockIdx.x] = red[0];
}

__global__ __launch_bounds__(256) void scan_final(const int* deg,
                                                  const int* __restrict__ tilesum,
                                                  int* __restrict__ rowptr,
                                                  int* cursor)
{
  __shared__ int lds[256];
  const int tid = threadIdx.x;
  int pre = 0;
  for (int t = 0; t < NTILES; ++t)
    if (t < blockIdx.x) pre += tilesum[t];

  int base = blockIdx.x * TILE + tid * 8;
  int d[8];
  int s = 0;
#pragma unroll
  for (int j = 0; j < 8; ++j) {
    int i = base + j;
    d[j] = (i < NN) ? deg[i] : 0;
    s += d[j];
  }
  lds[tid] = s;
  __syncthreads();
  for (int off = 1; off < 256; off <<= 1) {
    int t = (tid >= off) ? lds[tid - off] : 0;
    __syncthreads();
    lds[tid] += t;
    __syncthreads();
  }
  int run = pre + lds[tid] - s;
#pragma unroll
  for (int j = 0; j < 8; ++j) {
    int i = base + j;
    if (i < NN) {
      rowptr[i] = run;
      cursor[i] = run;
      run += d[j];
    }
  }
  if (blockIdx.x == NTILES - 1 && tid == 255)
    rowptr[NN] = pre + lds[255];
}

__global__ __launch_bounds__(256) void scatter_edges(
    const int* __restrict__ src, const int* __restrict__ dst, const int* __restrict__ ety,
    int* __restrict__ cursor, int* __restrict__ csr)
{
  int e = blockIdx.x * blockDim.x + threadIdx.x;
  if (e >= NE) return;
  int d = dst[e];
  int p = atomicAdd(&cursor[d], 1);
  csr[p] = src[e] | (ety[e] << 20);            // src:20 bits, ety:3 bits
}

// ---------------- Fused layer: gather (LDS) + GEMM ----------------
// Block = 32 nodes, 512 threads (8 waves), 3 blocks/CU (48 KB LDS).
// Phase 1: wave w gathers rows w*4..w*4+3 (4-node serial chain only):
//   gl[row][slot^(row&7)] = bf16( sum_e comp[et][b]*h[src][i] ).
// Phase 2: wave w -> m-tile (w>>2), ct pair (w&3)*2+{0,1}:
//   out[n][o] = sum_k [gl(n)|h(n)][k]*W[o][k], K=640, W LDS double-buffered
//   (T14: issue global early, ds_write after MFMAs). NN%32==0: no bounds checks.
template<int FINAL>
__global__ __launch_bounds__(512, 6) void rgcn_fused(
    const int* __restrict__ rowptr, const int* __restrict__ csr,
    const float* __restrict__ comp,   // [R,B]
    const short* __restrict__ hbf,    // [N,128] bf16
    const short* __restrict__ W8,     // [80][128][8] bf16 (slot = kb*128+o)
    const float* __restrict__ bias,   // [128]
    short* __restrict__ outH,         // [N,128] bf16 (FINAL=0)
    float* __restrict__ outF)         // [N,128] fp32 (FINAL=1)
{
  __shared__ bf16x8 gl[32][64];       // 32 KB gathered-g tile (swizzled slots)
  __shared__ bf16x8 wl[2][512];       // 16 KB W slice double-buffer

  const int tid  = threadIdx.x;
  const int wave = tid >> 6;          // 0..7
  const int lane = tid & 63;
  const int b  = lane >> 4;           // basis (gather) / k-group g8 (gemm)
  const int q  = lane & 15;           // col-slot (gather) / node r (gemm)
  const int base = blockIdx.x * 32;

  // gemm-phase identity
  const int mt = wave >> 2;           // m-tile 0..1
  const int ct0 = (wave & 3) * 2;     // ct pair
  const int mynode = base + mt * 16 + q;

  // prefetch self-loop h fragments (k = 512..639): lane (q=r, b=g8)
  const bf16x8* ha = reinterpret_cast<const bf16x8*>(hbf + (size_t)mynode * HH);
  bf16x8 hreg[4];
#pragma unroll
  for (int j = 0; j < 4; ++j) hreg[j] = ha[j * 4 + b];

  // ---------------- phase 1: gather (4 nodes per wave) ----------------
#pragma unroll 1
  for (int nn = 0; nn < 4; ++nn) {
    const int row = wave * 4 + nn;
    const int node = base + row;
    const int start = rowptr[node];
    const int end   = rowptr[node + 1];

    float acc[8] = {0.f, 0.f, 0.f, 0.f, 0.f, 0.f, 0.f, 0.f};
    int i = start;
    for (; i + 4 <= end; i += 4) {
      int e0 = csr[i], e1 = csr[i + 1], e2 = csr[i + 2], e3 = csr[i + 3];
      bf16x8 h0 = reinterpret_cast<const bf16x8*>(hbf + (size_t)(e0 & 0xFFFFF) * HH)[q];
      bf16x8 h1 = reinterpret_cast<const bf16x8*>(hbf + (size_t)(e1 & 0xFFFFF) * HH)[q];
      bf16x8 h2 = reinterpret_cast<const bf16x8*>(hbf + (size_t)(e2 & 0xFFFFF) * HH)[q];
      bf16x8 h3 = reinterpret_cast<const bf16x8*>(hbf + (size_t)(e3 & 0xFFFFF) * HH)[q];
      float c0 = comp[(e0 >> 20) * NB + b];
      float c1 = comp[(e1 >> 20) * NB + b];
      float c2 = comp[(e2 >> 20) * NB + b];
      float c3 = comp[(e3 >> 20) * NB + b];
#pragma unroll
      for (int j = 0; j < 8; ++j) acc[j] += bf2f(h0[j]) * c0;
#pragma unroll
      for (int j = 0; j < 8; ++j) acc[j] += bf2f(h1[j]) * c1;
#pragma unroll
      for (int j = 0; j < 8; ++j) acc[j] += bf2f(h2[j]) * c2;
#pragma unroll
      for (int j = 0; j < 8; ++j) acc[j] += bf2f(h3[j]) * c3;
    }
    for (; i < end; ++i) {
      int e0 = csr[i];
      bf16x8 h0 = reinterpret_cast<const bf16x8*>(hbf + (size_t)(e0 & 0xFFFFF) * HH)[q];
      float c0 = comp[(e0 >> 20) * NB + b];
#pragma unroll
      for (int j = 0; j < 8; ++j) acc[j] += bf2f(h0[j]) * c0;
    }

    bf16x8 o;
#pragma unroll
    for (int j = 0; j < 8; ++j) o[j] = f2bf(acc[j]);
    gl[row][lane ^ (row & 7)] = o;    // logical slot = b*16+q = lane
  }

  // stage W slice 0 (512 slots, 1 per thread, coalesced)
  const bf16x8* wsrc = reinterpret_cast<const bf16x8*>(W8);
  wl[0][tid] = wsrc[tid];
  __syncthreads();                    // gl + wl[0] visible

  // ---------------- phase 2: GEMM ----------------
  const int r  = q;
  const int g8 = b;

  f32x4 acc0 = {0.f, 0.f, 0.f, 0.f};
  f32x4 acc1 = {0.f, 0.f, 0.f, 0.f};

#pragma unroll 1
  for (int ks = 0; ks < 20; ++ks) {
    const int cur = ks & 1;
    bf16x8 nxt;
    if (ks < 19) nxt = wsrc[(ks + 1) * 512 + tid];   // issue early (T14)
    // A fragment: k = ks*32 + g8*8 + j ; logical slot = ks*4+g8
    bf16x8 a = (ks < 16) ? gl[mt * 16 + r][(ks * 4 + g8) ^ (r & 7)] : hreg[ks - 16];
    bf16x8 w0 = wl[cur][g8 * 128 + (ct0 + 0) * 16 + r];
    bf16x8 w1 = wl[cur][g8 * 128 + (ct0 + 1) * 16 + r];
    acc0 = __builtin_amdgcn_mfma_f32_16x16x32_bf16(w0, a, acc0, 0, 0, 0);
    acc1 = __builtin_amdgcn_mfma_f32_16x16x32_bf16(w1, a, acc1, 0, 0, 0);
    if (ks < 19) wl[cur ^ 1][tid] = nxt;             // write late
    __syncthreads();
  }

  // epilogue: D mapping (verified): node = r, o = ct*16 + g8*4 + reg
#pragma unroll
  for (int c = 0; c < 2; ++c) {
    const f32x4 acc = c ? acc1 : acc0;
    const int o = (ct0 + c) * 16 + g8 * 4;
    vfloat4 bs = *reinterpret_cast<const vfloat4*>(bias + o);
    if (FINAL) {
      vfloat4 x;
#pragma unroll
      for (int rr = 0; rr < 4; ++rr) x[rr] = acc[rr] + bs[rr];
      reinterpret_cast<vfloat4*>(outF + (size_t)mynode * HH)[(ct0 + c) * 4 + g8] = x;
    } else {
      ushort4v s;
#pragma unroll
      for (int rr = 0; rr < 4; ++rr)
        s[rr] = (unsigned short)f2bf(fmaxf(acc[rr] + bs[rr], 0.f));
      reinterpret_cast<ushort4v*>(outH + (size_t)mynode * HH)[(ct0 + c) * 4 + g8] = s;
    }
  }
}

extern "C" void kernel_launch(void* const* d_in, const int* in_sizes, int n_in,
                              void* d_out, int out_size, void* d_ws, size_t ws_size,
                              hipStream_t stream)
{
  const int*   srcp  = (const int*)d_in[1];
  const int*   dstp  = (const int*)d_in[2];
  const int*   etp   = (const int*)d_in[3];
  const float* emb   = (const float*)d_in[4];
  const float* V1    = (const float*)d_in[5];
  const float* comp1 = (const float*)d_in[6];
  const float* loop1 = (const float*)d_in[7];
  const float* bias1 = (const float*)d_in[8];
  const float* V2    = (const float*)d_in[9];
  const float* comp2 = (const float*)d_in[10];
  const float* loop2 = (const float*)d_in[11];
  const float* bias2 = (const float*)d_in[12];
  float* out = (float*)d_out;

  char* ws = (char*)d_ws;
  short* Wt1     = (short*)(ws);                         // 163,840 B
  short* Wt2     = (short*)(ws + 163840);                // 163,840 B
  short* hbf1    = (short*)(ws + 327680);                // 25,600,000 B
  short* hbf2    = (short*)(ws + 25927680);              // 25,600,000 B
  int*   deg     = (int*)  (ws + 51527680);              // 400,000 B (doubles as cursor)
  int*   rowptr  = (int*)  (ws + 51927680);              // 400,004 B
  int*   csr     = (int*)  (ws + 52327696);              // 2,400,000 B
  int*   tilesum = (int*)  (ws + 54727696);              // 196 B  (total ~54.7 MB)

  const int fused_blocks = NN / 32;                      // 3125 (NN % 32 == 0)
  const int e_blocks     = (NE + 255) / 256;

  // --- CSR build (once, reused by both layers) ---
  hipMemsetAsync(deg, 0, NN * sizeof(int), stream);
  hipLaunchKernelGGL(hist_deg, dim3(e_blocks), dim3(256), 0, stream, dstp, deg);
  hipLaunchKernelGGL(scan_tiles, dim3(NTILES), dim3(256), 0, stream, deg, tilesum);
  hipLaunchKernelGGL(scan_final, dim3(NTILES), dim3(256), 0, stream,
                     deg, tilesum, rowptr, deg);
  hipLaunchKernelGGL(scatter_edges, dim3(e_blocks), dim3(256), 0, stream,
                     srcp, dstp, etp, deg, csr);

  hipLaunchKernelGGL(build_wt, dim3(320), dim3(256), 0, stream, V1, loop1, Wt1);
  hipLaunchKernelGGL(build_wt, dim3(320), dim3(256), 0, stream, V2, loop2, Wt2);
  hipLaunchKernelGGL(cast_h, dim3(2048), dim3(256), 0, stream, emb, hbf1);

  // Layer 1 (fused gather+GEMM, bf16 relu output)
  hipLaunchKernelGGL((rgcn_fused<0>), dim3(fused_blocks), dim3(512), 0, stream,
                     rowptr, csr, comp1, hbf1, Wt1, bias1, hbf2, (float*)nullptr);

  // Layer 2 (fused, fp32 output)
  hipLaunchKernelGGL((rgcn_fused<1>), dim3(fused_blocks), dim3(512), 0, stream,
                     rowptr, csr, comp2, hbf2, Wt2, bias2, (short*)nullptr, out);
}

// Round 10
// 321.096 us; speedup vs baseline: 1.5421x; 1.1130x over previous
//
#include <hip/hip_runtime.h>
#include <hip/hip_bf16.h>

#define NN 100000
#define NE 600000
#define HH 128
#define NB 4
#define TILE 2048
#define NTILES ((NN + TILE - 1) / TILE)   // 49

typedef __attribute__((ext_vector_type(8))) short bf16x8;
typedef __attribute__((ext_vector_type(4))) float f32x4;
typedef __attribute__((ext_vector_type(4))) float vfloat4;
typedef __attribute__((ext_vector_type(4))) unsigned short ushort4v;

// round-to-nearest-even f32 -> bf16 bits (inputs are finite)
static __device__ __forceinline__ short f2bf(float f) {
  unsigned u = __float_as_uint(f);
  unsigned r = (u + 0x7fffu + ((u >> 16) & 1u)) >> 16;
  return (short)r;
}

static __device__ __forceinline__ float bf2f(short s) {
  unsigned u = (unsigned)(unsigned short)s;
  return __uint_as_float(u << 16);
}

// W8[kb][o][j] = W[o][k=kb*8+j], kb in [0,80), o in [0,128), j in [0,8).
// W[o][k]: k<512 -> V[k>>7][k&127][o] (= V flat [k*128+o]); else loopW[k-512][o].
__global__ __launch_bounds__(256) void build_wt(const float* __restrict__ V,
                                                const float* __restrict__ loopW,
                                                short* __restrict__ W8)
{
  int idx = blockIdx.x * blockDim.x + threadIdx.x;   // 320*256 = 81920
  int j  = idx & 7;
  int o  = (idx >> 3) & 127;
  int kb = idx >> 10;
  int k  = kb * 8 + j;
  float v;
  if (k < 512) v = V[(size_t)k * HH + o];
  else         v = loopW[(size_t)(k - 512) * HH + o];
  W8[idx] = f2bf(v);
}

// hbf = bf16(emb), vectorized (8 elems/thread/iter)
__global__ __launch_bounds__(256) void cast_h(const float* __restrict__ in,
                                              short* __restrict__ out)
{
  const int n8 = NN * HH / 8;
  for (int i = blockIdx.x * blockDim.x + threadIdx.x; i < n8; i += gridDim.x * blockDim.x) {
    const vfloat4* p = reinterpret_cast<const vfloat4*>(in + i * 8);
    vfloat4 a = p[0], b = p[1];
    bf16x8 o;
#pragma unroll
    for (int j = 0; j < 4; ++j) { o[j] = f2bf(a[j]); o[j + 4] = f2bf(b[j]); }
    reinterpret_cast<bf16x8*>(out)[i] = o;
  }
}

// ---------------- CSR build ----------------

__global__ __launch_bounds__(256) void hist_deg(const int* __restrict__ dst,
                                                int* __restrict__ deg)
{
  int e = blockIdx.x * blockDim.x + threadIdx.x;
  if (e < NE) atomicAdd(&deg[dst[e]], 1);
}

__global__ __launch_bounds__(256) void scan_tiles(const int* __restrict__ deg,
                                                  int* __restrict__ tilesum)
{
  __shared__ int red[256];
  const int tid = threadIdx.x;
  int base = blockIdx.x * TILE + tid * 8;
  int s = 0;
#pragma unroll
  for (int j = 0; j < 8; ++j) {
    int i = base + j;
    if (i < NN) s += deg[i];
  }
  red[tid] = s;
  __syncthreads();
  for (int off = 128; off > 0; off >>= 1) {
    if (tid < off) red[tid] += red[tid + off];
    __syncthreads();
  }
  if (tid == 0) tilesum[blockIdx.x] = red[0];
}

__global__ __launch_bounds__(256) void scan_final(const int* deg,
                                                  const int* __restrict__ tilesum,
                                                  int* __restrict__ rowptr,
                                                  int* cursor)
{
  __shared__ int lds[256];
  const int tid = threadIdx.x;
  int pre = 0;
  for (int t = 0; t < NTILES; ++t)
    if (t < blockIdx.x) pre += tilesum[t];

  int base = blockIdx.x * TILE + tid * 8;
  int d[8];
  int s = 0;
#pragma unroll
  for (int j = 0; j < 8; ++j) {
    int i = base + j;
    d[j] = (i < NN) ? deg[i] : 0;
    s += d[j];
  }
  lds[tid] = s;
  __syncthreads();
  for (int off = 1; off < 256; off <<= 1) {
    int t = (tid >= off) ? lds[tid - off] : 0;
    __syncthreads();
    lds[tid] += t;
    __syncthreads();
  }
  int run = pre + lds[tid] - s;
#pragma unroll
  for (int j = 0; j < 8; ++j) {
    int i = base + j;
    if (i < NN) {
      rowptr[i] = run;
      cursor[i] = run;
      run += d[j];
    }
  }
  if (blockIdx.x == NTILES - 1 && tid == 255)
    rowptr[NN] = pre + lds[255];
}

__global__ __launch_bounds__(256) void scatter_edges(
    const int* __restrict__ src, const int* __restrict__ dst, const int* __restrict__ ety,
    int* __restrict__ cursor, int* __restrict__ csr)
{
  int e = blockIdx.x * blockDim.x + threadIdx.x;
  if (e >= NE) return;
  int d = dst[e];
  int p = atomicAdd(&cursor[d], 1);
  csr[p] = src[e] | (ety[e] << 20);            // src:20 bits, ety:3 bits
}

// ---------------- Fused layer: gather (LDS) + GEMM ----------------
// Block = 32 nodes, 512 threads (8 waves), 3 blocks/CU (48 KB LDS).
// Phase 1 (restructured R10): wave handles rows w*4..w*4+3 as TWO PAIRS.
// Per pair, both nodes' edge quads (8 hbf rows + coeffs) are issued before any
// FMA consumes them (8 rows in flight/wave, no serial remainder: quads are
// masked with c=0). CSR bounds go through readfirstlane -> s_load path.
// Phase 2: wave w -> m-tile (w>>2), ct pair (w&3)*2+{0,1}; W LDS dbuf (R7).
// NOTE: no early returns -- every thread reaches every __syncthreads.
template<int FINAL>
__global__ __launch_bounds__(512, 6) void rgcn_fused(
    const int* __restrict__ rowptr, const int* __restrict__ csr,
    const float* __restrict__ comp,   // [R,B]
    const short* __restrict__ hbf,    // [N,128] bf16
    const short* __restrict__ W8,     // [80][128][8] bf16 (slot = kb*128+o)
    const float* __restrict__ bias,   // [128]
    short* __restrict__ outH,         // [N,128] bf16 (FINAL=0)
    float* __restrict__ outF)         // [N,128] fp32 (FINAL=1)
{
  __shared__ bf16x8 gl[32][64];       // 32 KB gathered-g tile (swizzled slots)
  __shared__ bf16x8 wl[2][512];       // 16 KB W slice double-buffer

  const int tid  = threadIdx.x;
  const int wave = tid >> 6;          // 0..7
  const int lane = tid & 63;
  const int b  = lane >> 4;           // basis (gather) / k-group g8 (gemm)
  const int q  = lane & 15;           // col-slot (gather) / node r (gemm)
  const int base = blockIdx.x * 32;

  // gemm-phase identity
  const int mt = wave >> 2;           // m-tile 0..1
  const int ct0 = (wave & 3) * 2;     // ct pair
  const int mynode = base + mt * 16 + q;

  // ---------------- phase 1: gather (2 node-pairs per wave) ----------------
#pragma unroll 1
  for (int pp = 0; pp < 2; ++pp) {
    const int row0 = wave * 4 + pp * 2;
    const int row1 = row0 + 1;
    // 3 consecutive rowptr entries; scalarized -> csr indexing goes s_load
    int       i0 = __builtin_amdgcn_readfirstlane(rowptr[base + row0]);
    const int E0 = __builtin_amdgcn_readfirstlane(rowptr[base + row0 + 1]);
    int       i1 = E0;
    const int E1 = __builtin_amdgcn_readfirstlane(rowptr[base + row1 + 1]);

    float a0[8] = {0.f, 0.f, 0.f, 0.f, 0.f, 0.f, 0.f, 0.f};
    float a1[8] = {0.f, 0.f, 0.f, 0.f, 0.f, 0.f, 0.f, 0.f};

    while (i0 < E0 || i1 < E1) {
      const bool d0 = i0 < E0, d1 = i1 < E1;
      bf16x8 H[8];
      float  C[8];
      if (d0) {
#pragma unroll
        for (int j = 0; j < 4; ++j) {
          const int idx = i0 + j;
          const bool v = idx < E0;
          const int e = csr[v ? idx : E0 - 1];
          H[j] = reinterpret_cast<const bf16x8*>(hbf + (size_t)(e & 0xFFFFF) * HH)[q];
          C[j] = v ? comp[(e >> 20) * NB + b] : 0.f;
        }
      }
      if (d1) {
#pragma unroll
        for (int j = 0; j < 4; ++j) {
          const int idx = i1 + j;
          const bool v = idx < E1;
          const int e = csr[v ? idx : E1 - 1];
          H[4 + j] = reinterpret_cast<const bf16x8*>(hbf + (size_t)(e & 0xFFFFF) * HH)[q];
          C[4 + j] = v ? comp[(e >> 20) * NB + b] : 0.f;
        }
      }
      if (d0) {
#pragma unroll
        for (int j = 0; j < 4; ++j)
#pragma unroll
          for (int k = 0; k < 8; ++k) a0[k] += bf2f(H[j][k]) * C[j];
        i0 += 4;
      }
      if (d1) {
#pragma unroll
        for (int j = 0; j < 4; ++j)
#pragma unroll
          for (int k = 0; k < 8; ++k) a1[k] += bf2f(H[4 + j][k]) * C[4 + j];
        i1 += 4;
      }
    }

    bf16x8 o0, o1;
#pragma unroll
    for (int j = 0; j < 8; ++j) { o0[j] = f2bf(a0[j]); o1[j] = f2bf(a1[j]); }
    gl[row0][lane ^ (row0 & 7)] = o0;   // logical slot = b*16+q = lane
    gl[row1][lane ^ (row1 & 7)] = o1;
  }

  // prefetch self-loop h fragments (k = 512..639): lane (q=r, b=g8)
  const bf16x8* ha = reinterpret_cast<const bf16x8*>(hbf + (size_t)mynode * HH);
  bf16x8 hreg[4];
#pragma unroll
  for (int j = 0; j < 4; ++j) hreg[j] = ha[j * 4 + b];

  // stage W slice 0 (512 slots, 1 per thread, coalesced)
  const bf16x8* wsrc = reinterpret_cast<const bf16x8*>(W8);
  wl[0][tid] = wsrc[tid];
  __syncthreads();                    // gl + wl[0] visible

  // ---------------- phase 2: GEMM ----------------
  const int r  = q;
  const int g8 = b;

  f32x4 acc0 = {0.f, 0.f, 0.f, 0.f};
  f32x4 acc1 = {0.f, 0.f, 0.f, 0.f};

#pragma unroll 1
  for (int ks = 0; ks < 20; ++ks) {
    const int cur = ks & 1;
    bf16x8 nxt;
    if (ks < 19) nxt = wsrc[(ks + 1) * 512 + tid];   // issue early (T14)
    // A fragment: k = ks*32 + g8*8 + j ; logical slot = ks*4+g8
    bf16x8 a = (ks < 16) ? gl[mt * 16 + r][(ks * 4 + g8) ^ (r & 7)] : hreg[ks - 16];
    bf16x8 w0 = wl[cur][g8 * 128 + (ct0 + 0) * 16 + r];
    bf16x8 w1 = wl[cur][g8 * 128 + (ct0 + 1) * 16 + r];
    acc0 = __builtin_amdgcn_mfma_f32_16x16x32_bf16(w0, a, acc0, 0, 0, 0);
    acc1 = __builtin_amdgcn_mfma_f32_16x16x32_bf16(w1, a, acc1, 0, 0, 0);
    if (ks < 19) wl[cur ^ 1][tid] = nxt;             // write late
    __syncthreads();
  }

  // epilogue: D mapping (verified): node = r, o = ct*16 + g8*4 + reg
#pragma unroll
  for (int c = 0; c < 2; ++c) {
    const f32x4 acc = c ? acc1 : acc0;
    const int o = (ct0 + c) * 16 + g8 * 4;
    vfloat4 bs = *reinterpret_cast<const vfloat4*>(bias + o);
    if (FINAL) {
      vfloat4 x;
#pragma unroll
      for (int rr = 0; rr < 4; ++rr) x[rr] = acc[rr] + bs[rr];
      reinterpret_cast<vfloat4*>(outF + (size_t)mynode * HH)[(ct0 + c) * 4 + g8] = x;
    } else {
      ushort4v s;
#pragma unroll
      for (int rr = 0; rr < 4; ++rr)
        s[rr] = (unsigned short)f2bf(fmaxf(acc[rr] + bs[rr], 0.f));
      reinterpret_cast<ushort4v*>(outH + (size_t)mynode * HH)[(ct0 + c) * 4 + g8] = s;
    }
  }
}

extern "C" void kernel_launch(void* const* d_in, const int* in_sizes, int n_in,
                              void* d_out, int out_size, void* d_ws, size_t ws_size,
                              hipStream_t stream)
{
  const int*   srcp  = (const int*)d_in[1];
  const int*   dstp  = (const int*)d_in[2];
  const int*   etp   = (const int*)d_in[3];
  const float* emb   = (const float*)d_in[4];
  const float* V1    = (const float*)d_in[5];
  const float* comp1 = (const float*)d_in[6];
  const float* loop1 = (const float*)d_in[7];
  const float* bias1 = (const float*)d_in[8];
  const float* V2    = (const float*)d_in[9];
  const float* comp2 = (const float*)d_in[10];
  const float* loop2 = (const float*)d_in[11];
  const float* bias2 = (const float*)d_in[12];
  float* out = (float*)d_out;

  char* ws = (char*)d_ws;
  short* Wt1     = (short*)(ws);                         // 163,840 B
  short* Wt2     = (short*)(ws + 163840);                // 163,840 B
  short* hbf1    = (short*)(ws + 327680);                // 25,600,000 B
  short* hbf2    = (short*)(ws + 25927680);              // 25,600,000 B
  int*   deg     = (int*)  (ws + 51527680);              // 400,000 B (doubles as cursor)
  int*   rowptr  = (int*)  (ws + 51927680);              // 400,004 B
  int*   csr     = (int*)  (ws + 52327696);              // 2,400,000 B
  int*   tilesum = (int*)  (ws + 54727696);              // 196 B  (total ~54.7 MB)

  const int fused_blocks = NN / 32;                      // 3125 (NN % 32 == 0)
  const int e_blocks     = (NE + 255) / 256;

  // --- CSR build (once, reused by both layers) ---
  hipMemsetAsync(deg, 0, NN * sizeof(int), stream);
  hipLaunchKernelGGL(hist_deg, dim3(e_blocks), dim3(256), 0, stream, dstp, deg);
  hipLaunchKernelGGL(scan_tiles, dim3(NTILES), dim3(256), 0, stream, deg, tilesum);
  hipLaunchKernelGGL(scan_final, dim3(NTILES), dim3(256), 0, stream,
                     deg, tilesum, rowptr, deg);
  hipLaunchKernelGGL(scatter_edges, dim3(e_blocks), dim3(256), 0, stream,
                     srcp, dstp, etp, deg, csr);

  hipLaunchKernelGGL(build_wt, dim3(320), dim3(256), 0, stream, V1, loop1, Wt1);
  hipLaunchKernelGGL(build_wt, dim3(320), dim3(256), 0, stream, V2, loop2, Wt2);
  hipLaunchKernelGGL(cast_h, dim3(2048), dim3(256), 0, stream, emb, hbf1);

  // Layer 1 (fused gather+GEMM, bf16 relu output)
  hipLaunchKernelGGL((rgcn_fused<0>), dim3(fused_blocks), dim3(512), 0, stream,
                     rowptr, csr, comp1, hbf1, Wt1, bias1, hbf2, (float*)nullptr);

  // Layer 2 (fused, fp32 output)
  hipLaunchKernelGGL((rgcn_fused<1>), dim3(fused_blocks), dim3(512), 0, stream,
                     rowptr, csr, comp2, hbf2, Wt2, bias2, (short*)nullptr, out);
}

// Round 11
// 317.861 us; speedup vs baseline: 1.5578x; 1.0102x over previous
//
#include <hip/hip_runtime.h>
#include <hip/hip_bf16.h>

#define NN 100000
#define NE 600000
#define HH 128
#define NB 4
#define TILE 2048
#define NTILES ((NN + TILE - 1) / TILE)   // 49

typedef __attribute__((ext_vector_type(8))) short bf16x8;
typedef __attribute__((ext_vector_type(4))) float f32x4;
typedef __attribute__((ext_vector_type(4))) float vfloat4;
typedef __attribute__((ext_vector_type(4))) unsigned short ushort4v;

// round-to-nearest-even f32 -> bf16 bits (inputs are finite)
static __device__ __forceinline__ short f2bf(float f) {
  unsigned u = __float_as_uint(f);
  unsigned r = (u + 0x7fffu + ((u >> 16) & 1u)) >> 16;
  return (short)r;
}

static __device__ __forceinline__ float bf2f(short s) {
  unsigned u = (unsigned)(unsigned short)s;
  return __uint_as_float(u << 16);
}

// W8[kb][o][j] = W[o][k=kb*8+j], kb in [0,80), o in [0,128), j in [0,8).
// W[o][k]: k<512 -> V[k>>7][k&127][o] (= V flat [k*128+o]); else loopW[k-512][o].
__global__ __launch_bounds__(256) void build_wt(const float* __restrict__ V,
                                                const float* __restrict__ loopW,
                                                short* __restrict__ W8)
{
  int idx = blockIdx.x * blockDim.x + threadIdx.x;   // 320*256 = 81920
  int j  = idx & 7;
  int o  = (idx >> 3) & 127;
  int kb = idx >> 10;
  int k  = kb * 8 + j;
  float v;
  if (k < 512) v = V[(size_t)k * HH + o];
  else         v = loopW[(size_t)(k - 512) * HH + o];
  W8[idx] = f2bf(v);
}

// hbf = bf16(emb), vectorized (8 elems/thread/iter)
__global__ __launch_bounds__(256) void cast_h(const float* __restrict__ in,
                                              short* __restrict__ out)
{
  const int n8 = NN * HH / 8;
  for (int i = blockIdx.x * blockDim.x + threadIdx.x; i < n8; i += gridDim.x * blockDim.x) {
    const vfloat4* p = reinterpret_cast<const vfloat4*>(in + i * 8);
    vfloat4 a = p[0], b = p[1];
    bf16x8 o;
#pragma unroll
    for (int j = 0; j < 4; ++j) { o[j] = f2bf(a[j]); o[j + 4] = f2bf(b[j]); }
    reinterpret_cast<bf16x8*>(out)[i] = o;
  }
}

// ---------------- CSR build ----------------

__global__ __launch_bounds__(256) void hist_deg(const int* __restrict__ dst,
                                                int* __restrict__ deg)
{
  int e = blockIdx.x * blockDim.x + threadIdx.x;
  if (e < NE) atomicAdd(&deg[dst[e]], 1);
}

__global__ __launch_bounds__(256) void scan_tiles(const int* __restrict__ deg,
                                                  int* __restrict__ tilesum)
{
  __shared__ int red[256];
  const int tid = threadIdx.x;
  int base = blockIdx.x * TILE + tid * 8;
  int s = 0;
#pragma unroll
  for (int j = 0; j < 8; ++j) {
    int i = base + j;
    if (i < NN) s += deg[i];
  }
  red[tid] = s;
  __syncthreads();
  for (int off = 128; off > 0; off >>= 1) {
    if (tid < off) red[tid] += red[tid + off];
    __syncthreads();
  }
  if (tid == 0) tilesum[blockIdx.x] = red[0];
}

__global__ __launch_bounds__(256) void scan_final(const int* deg,
                                                  const int* __restrict__ tilesum,
                                                  int* __restrict__ rowptr,
                                                  int* cursor)
{
  __shared__ int lds[256];
  const int tid = threadIdx.x;
  int pre = 0;
  for (int t = 0; t < NTILES; ++t)
    if (t < blockIdx.x) pre += tilesum[t];

  int base = blockIdx.x * TILE + tid * 8;
  int d[8];
  int s = 0;
#pragma unroll
  for (int j = 0; j < 8; ++j) {
    int i = base + j;
    d[j] = (i < NN) ? deg[i] : 0;
    s += d[j];
  }
  lds[tid] = s;
  __syncthreads();
  for (int off = 1; off < 256; off <<= 1) {
    int t = (tid >= off) ? lds[tid - off] : 0;
    __syncthreads();
    lds[tid] += t;
    __syncthreads();
  }
  int run = pre + lds[tid] - s;
#pragma unroll
  for (int j = 0; j < 8; ++j) {
    int i = base + j;
    if (i < NN) {
      rowptr[i] = run;
      cursor[i] = run;
      run += d[j];
    }
  }
  if (blockIdx.x == NTILES - 1 && tid == 255)
    rowptr[NN] = pre + lds[255];
}

__global__ __launch_bounds__(256) void scatter_edges(
    const int* __restrict__ src, const int* __restrict__ dst, const int* __restrict__ ety,
    int* __restrict__ cursor, int* __restrict__ csr)
{
  int e = blockIdx.x * blockDim.x + threadIdx.x;
  if (e >= NE) return;
  int d = dst[e];
  int p = atomicAdd(&cursor[d], 1);
  csr[p] = src[e] | (ety[e] << 20);            // src:20 bits, ety:3 bits
}

// ---------------- Fused layer: gather (LDS) + GEMM ----------------
// Block = 32 nodes, 512 threads (8 waves), 3 blocks/CU (48 KB LDS).
// Phase 1: wave handles rows w*4..w*4+3 as two pairs; per pair both nodes'
// masked edge-quads issued before any FMA (8 rows in flight, no remainder).
// Phase 2: wave w -> m-tile (w>>2), ct pair (w&3)*2+{0,1}; W LDS dbuf (R7).
// Epilogue (R11): D staged into LDS (gl reused, swizzled), then 512 threads
// copy out FULL contiguous rows -> no partial-sector write amplification.
// NOTE: no early returns -- every thread reaches every __syncthreads.
template<int FINAL>
__global__ __launch_bounds__(512, 6) void rgcn_fused(
    const int* __restrict__ rowptr, const int* __restrict__ csr,
    const float* __restrict__ comp,   // [R,B]
    const short* __restrict__ hbf,    // [N,128] bf16
    const short* __restrict__ W8,     // [80][128][8] bf16 (slot = kb*128+o)
    const float* __restrict__ bias,   // [128]
    short* __restrict__ outH,         // [N,128] bf16 (FINAL=0)
    float* __restrict__ outF)         // [N,128] fp32 (FINAL=1)
{
  __shared__ bf16x8 gl[32][64];       // 32 KB gathered-g tile (swizzled slots)
  __shared__ bf16x8 wl[2][512];       // 16 KB W slice double-buffer

  const int tid  = threadIdx.x;
  const int wave = tid >> 6;          // 0..7
  const int lane = tid & 63;
  const int b  = lane >> 4;           // basis (gather) / k-group g8 (gemm)
  const int q  = lane & 15;           // col-slot (gather) / node r (gemm)
  const int base = blockIdx.x * 32;

  // gemm-phase identity
  const int mt = wave >> 2;           // m-tile 0..1
  const int ct0 = (wave & 3) * 2;     // ct pair
  const int mynode = base + mt * 16 + q;

  // T14: issue W slice-0 global load now; ds_write after gather
  const bf16x8* wsrc = reinterpret_cast<const bf16x8*>(W8);
  bf16x8 w0reg = wsrc[tid];

  // ---------------- phase 1: gather (2 node-pairs per wave) ----------------
#pragma unroll 1
  for (int pp = 0; pp < 2; ++pp) {
    const int row0 = wave * 4 + pp * 2;
    const int row1 = row0 + 1;
    // 3 consecutive rowptr entries; scalarized -> csr indexing goes s_load
    int       i0 = __builtin_amdgcn_readfirstlane(rowptr[base + row0]);
    const int E0 = __builtin_amdgcn_readfirstlane(rowptr[base + row0 + 1]);
    int       i1 = E0;
    const int E1 = __builtin_amdgcn_readfirstlane(rowptr[base + row1 + 1]);

    float a0[8] = {0.f, 0.f, 0.f, 0.f, 0.f, 0.f, 0.f, 0.f};
    float a1[8] = {0.f, 0.f, 0.f, 0.f, 0.f, 0.f, 0.f, 0.f};

    while (i0 < E0 || i1 < E1) {
      const bool d0 = i0 < E0, d1 = i1 < E1;
      bf16x8 H[8];
      float  C[8];
      if (d0) {
#pragma unroll
        for (int j = 0; j < 4; ++j) {
          const int idx = i0 + j;
          const bool v = idx < E0;
          const int e = csr[v ? idx : E0 - 1];
          H[j] = reinterpret_cast<const bf16x8*>(hbf + (size_t)(e & 0xFFFFF) * HH)[q];
          C[j] = v ? comp[(e >> 20) * NB + b] : 0.f;
        }
      }
      if (d1) {
#pragma unroll
        for (int j = 0; j < 4; ++j) {
          const int idx = i1 + j;
          const bool v = idx < E1;
          const int e = csr[v ? idx : E1 - 1];
          H[4 + j] = reinterpret_cast<const bf16x8*>(hbf + (size_t)(e & 0xFFFFF) * HH)[q];
          C[4 + j] = v ? comp[(e >> 20) * NB + b] : 0.f;
        }
      }
      if (d0) {
#pragma unroll
        for (int j = 0; j < 4; ++j)
#pragma unroll
          for (int k = 0; k < 8; ++k) a0[k] += bf2f(H[j][k]) * C[j];
        i0 += 4;
      }
      if (d1) {
#pragma unroll
        for (int j = 0; j < 4; ++j)
#pragma unroll
          for (int k = 0; k < 8; ++k) a1[k] += bf2f(H[4 + j][k]) * C[4 + j];
        i1 += 4;
      }
    }

    bf16x8 o0, o1;
#pragma unroll
    for (int j = 0; j < 8; ++j) { o0[j] = f2bf(a0[j]); o1[j] = f2bf(a1[j]); }
    gl[row0][lane ^ (row0 & 7)] = o0;   // logical slot = b*16+q = lane
    gl[row1][lane ^ (row1 & 7)] = o1;
  }

  // prefetch self-loop h fragments (k = 512..639): lane (q=r, b=g8)
  const bf16x8* ha = reinterpret_cast<const bf16x8*>(hbf + (size_t)mynode * HH);
  bf16x8 hreg[4];
#pragma unroll
  for (int j = 0; j < 4; ++j) hreg[j] = ha[j * 4 + b];

  // stage W slice 0 (reg was loaded before gather)
  wl[0][tid] = w0reg;
  __syncthreads();                    // gl + wl[0] visible

  // ---------------- phase 2: GEMM ----------------
  const int r  = q;
  const int g8 = b;

  f32x4 acc0 = {0.f, 0.f, 0.f, 0.f};
  f32x4 acc1 = {0.f, 0.f, 0.f, 0.f};

#pragma unroll 1
  for (int ks = 0; ks < 20; ++ks) {
    const int cur = ks & 1;
    bf16x8 nxt;
    if (ks < 19) nxt = wsrc[(ks + 1) * 512 + tid];   // issue early (T14)
    // A fragment: k = ks*32 + g8*8 + j ; logical slot = ks*4+g8
    bf16x8 a = (ks < 16) ? gl[mt * 16 + r][(ks * 4 + g8) ^ (r & 7)] : hreg[ks - 16];
    bf16x8 w0 = wl[cur][g8 * 128 + (ct0 + 0) * 16 + r];
    bf16x8 w1 = wl[cur][g8 * 128 + (ct0 + 1) * 16 + r];
    acc0 = __builtin_amdgcn_mfma_f32_16x16x32_bf16(w0, a, acc0, 0, 0, 0);
    acc1 = __builtin_amdgcn_mfma_f32_16x16x32_bf16(w1, a, acc1, 0, 0, 0);
    if (ks < 19) wl[cur ^ 1][tid] = nxt;             // write late
    __syncthreads();
  }

  // ---- epilogue: stage D in LDS (gl is dead after the ks=19 barrier),
  //      then coalesced full-row writes (no partial-sector amplification) ----
  // D mapping (verified): node = r, o = ct*16 + g8*4 + reg
  if (FINAL) {
    float* glf = reinterpret_cast<float*>(gl);       // [32 rows][128 f32] swizzled
#pragma unroll
    for (int c = 0; c < 2; ++c) {
      const f32x4 acc = c ? acc1 : acc0;
      const int row = mt * 16 + r;
      const int o = (ct0 + c) * 16 + g8 * 4;
      vfloat4 bs = *reinterpret_cast<const vfloat4*>(bias + o);
      vfloat4 x;
#pragma unroll
      for (int rr = 0; rr < 4; ++rr) x[rr] = acc[rr] + bs[rr];
      const int s = (ct0 + c) * 4 + g8;              // 16B slot in row (0..31)
      const int phys = s ^ (row & 7);
      *reinterpret_cast<vfloat4*>(glf + row * 128 + phys * 4) = x;
    }
    __syncthreads();
#pragma unroll
    for (int p = 0; p < 2; ++p) {
      const int flat = p * 512 + tid;                // 1024 slots of 16B
      const int row = flat >> 5, s = flat & 31;
      const int phys = s ^ (row & 7);
      vfloat4 x = *reinterpret_cast<const vfloat4*>(glf + row * 128 + phys * 4);
      *reinterpret_cast<vfloat4*>(outF + (size_t)(base + row) * HH + s * 4) = x;
    }
  } else {
    short* glb = reinterpret_cast<short*>(gl);       // [32 rows][128 bf16] swizzled
#pragma unroll
    for (int c = 0; c < 2; ++c) {
      const f32x4 acc = c ? acc1 : acc0;
      const int row = mt * 16 + r;
      const int o = (ct0 + c) * 16 + g8 * 4;
      vfloat4 bs = *reinterpret_cast<const vfloat4*>(bias + o);
      ushort4v sv;
#pragma unroll
      for (int rr = 0; rr < 4; ++rr)
        sv[rr] = (unsigned short)f2bf(fmaxf(acc[rr] + bs[rr], 0.f));
      const int u8 = (ct0 + c) * 4 + g8;             // 8B unit in row (0..31)
      const int phys16 = (u8 >> 1) ^ (row & 7);      // swizzle at 16B granularity
      *reinterpret_cast<ushort4v*>(glb + row * 128 + phys16 * 8 + (u8 & 1) * 4) = sv;
    }
    __syncthreads();
    {
      const int row = tid >> 4, s16 = tid & 15;      // 512 slots of 16B
      const int phys = s16 ^ (row & 7);
      bf16x8 x = *reinterpret_cast<const bf16x8*>(glb + row * 128 + phys * 8);
      *reinterpret_cast<bf16x8*>(outH + (size_t)(base + row) * HH + s16 * 8) = x;
    }
  }
}

extern "C" void kernel_launch(void* const* d_in, const int* in_sizes, int n_in,
                              void* d_out, int out_size, void* d_ws, size_t ws_size,
                              hipStream_t stream)
{
  const int*   srcp  = (const int*)d_in[1];
  const int*   dstp  = (const int*)d_in[2];
  const int*   etp   = (const int*)d_in[3];
  const float* emb   = (const float*)d_in[4];
  const float* V1    = (const float*)d_in[5];
  const float* comp1 = (const float*)d_in[6];
  const float* loop1 = (const float*)d_in[7];
  const float* bias1 = (const float*)d_in[8];
  const float* V2    = (const float*)d_in[9];
  const float* comp2 = (const float*)d_in[10];
  const float* loop2 = (const float*)d_in[11];
  const float* bias2 = (const float*)d_in[12];
  float* out = (float*)d_out;

  char* ws = (char*)d_ws;
  short* Wt1     = (short*)(ws);                         // 163,840 B
  short* Wt2     = (short*)(ws + 163840);                // 163,840 B
  short* hbf1    = (short*)(ws + 327680);                // 25,600,000 B
  short* hbf2    = (short*)(ws + 25927680);              // 25,600,000 B
  int*   deg     = (int*)  (ws + 51527680);              // 400,000 B (doubles as cursor)
  int*   rowptr  = (int*)  (ws + 51927680);              // 400,004 B
  int*   csr     = (int*)  (ws + 52327696);              // 2,400,000 B
  int*   tilesum = (int*)  (ws + 54727696);              // 196 B  (total ~54.7 MB)

  const int fused_blocks = NN / 32;                      // 3125 (NN % 32 == 0)
  const int e_blocks     = (NE + 255) / 256;

  // --- CSR build (once, reused by both layers) ---
  hipMemsetAsync(deg, 0, NN * sizeof(int), stream);
  hipLaunchKernelGGL(hist_deg, dim3(e_blocks), dim3(256), 0, stream, dstp, deg);
  hipLaunchKernelGGL(scan_tiles, dim3(NTILES), dim3(256), 0, stream, deg, tilesum);
  hipLaunchKernelGGL(scan_final, dim3(NTILES), dim3(256), 0, stream,
                     deg, tilesum, rowptr, deg);
  hipLaunchKernelGGL(scatter_edges, dim3(e_blocks), dim3(256), 0, stream,
                     srcp, dstp, etp, deg, csr);

  hipLaunchKernelGGL(build_wt, dim3(320), dim3(256), 0, stream, V1, loop1, Wt1);
  hipLaunchKernelGGL(build_wt, dim3(320), dim3(256), 0, stream, V2, loop2, Wt2);
  hipLaunchKernelGGL(cast_h, dim3(2048), dim3(256), 0, stream, emb, hbf1);

  // Layer 1 (fused gather+GEMM, bf16 relu output)
  hipLaunchKernelGGL((rgcn_fused<0>), dim3(fused_blocks), dim3(512), 0, stream,
                     rowptr, csr, comp1, hbf1, Wt1, bias1, hbf2, (float*)nullptr);

  // Layer 2 (fused, fp32 output)
  hipLaunchKernelGGL((rgcn_fused<1>), dim3(fused_blocks), dim3(512), 0, stream,
                     rowptr, csr, comp2, hbf2, Wt2, bias2, (short*)nullptr, out);
}